// Round 2
// baseline (307.105 us; speedup 1.0000x reference)
//
#include <hip/hip_runtime.h>
#include <math.h>

// Problem constants (B,C,H,W) = (8,128,256,256), Ch = 64
constexpr int Bn = 8, Cn = 128, ChN = 64, Hn = 256, Wn = 256;
constexpr long long HWn  = (long long)Hn * Wn;   // 65536
constexpr long long CHWn = (long long)Cn * HWn;  // 8388608

// Pre-kernel: transpose w1 (64x128, o-major) -> w1t (128x64, c-major) so the
// main kernel's per-c weight reads are contiguous uniform addresses
// (s_load_dwordx16-friendly).
__global__ void prep_w1t(const float* __restrict__ w1, float* __restrict__ w1t) {
    int idx = blockIdx.x * blockDim.x + threadIdx.x;
    if (idx < ChN * Cn) {
        int o = idx >> 7;     // / 128
        int c = idx & 127;    // % 128
        w1t[c * ChN + o] = w1[idx];
    }
}

__device__ __forceinline__ float softplus_f(float x) {
    // log(1+exp(x)) = max(x,0) + log1p(exp(-|x|))
    return fmaxf(x, 0.0f) + log1pf(expf(-fabsf(x)));
}

__global__ __launch_bounds__(256) void fused_lap(
    const float* __restrict__ u,
    const float* __restrict__ wi,
    const float* __restrict__ w1t,
    const float* __restrict__ b1,
    const float* __restrict__ w2,
    const float* __restrict__ b2,
    float* __restrict__ out)
{
    int p = blockIdx.x * 256 + threadIdx.x;   // pixel id in [0, B*H*W)
    int j = p & (Wn - 1);
    int i = (p >> 8) & (Hn - 1);
    int b = p >> 16;

    size_t pixoff = (size_t)b * CHWn + (size_t)i * Wn + (size_t)j;

    // ---- phase 1: h[o] = relu(sum_c wi[c] * w1[o][c] + b1[o]) ----
    float h[ChN];
    #pragma unroll
    for (int o = 0; o < ChN; ++o) h[o] = b1[o];

    const float* wip = wi + pixoff;
    #pragma unroll 2
    for (int c = 0; c < Cn; ++c) {
        float x = wip[(size_t)c * HWn];
        const float4* wrow = (const float4*)(w1t + c * ChN);
        #pragma unroll
        for (int q = 0; q < ChN / 4; ++q) {
            float4 wv = wrow[q];
            h[4*q+0] = fmaf(wv.x, x, h[4*q+0]);
            h[4*q+1] = fmaf(wv.y, x, h[4*q+1]);
            h[4*q+2] = fmaf(wv.z, x, h[4*q+2]);
            h[4*q+3] = fmaf(wv.w, x, h[4*q+3]);
        }
    }

    // ---- phase 2: w[k] = softplus(sum_o relu(h[o]) * w2[k][o] + b2[k]) ----
    float a0 = b2[0], a1 = b2[1], a2 = b2[2], a3 = b2[3];
    #pragma unroll
    for (int o = 0; o < ChN; ++o) {
        float hv = fmaxf(h[o], 0.0f);
        a0 = fmaf(w2[0*ChN + o], hv, a0);
        a1 = fmaf(w2[1*ChN + o], hv, a1);
        a2 = fmaf(w2[2*ChN + o], hv, a2);
        a3 = fmaf(w2[3*ChN + o], hv, a3);
    }
    float wu = softplus_f(a0);   // up    -> u[i-1][j]
    float wd = softplus_f(a1);   // down  -> u[i+1][j]
    float wl = softplus_f(a2);   // left  -> u[i][j-1]
    float wr = softplus_f(a3);   // right -> u[i][j+1]
    float wsum = (wu + wd) + (wl + wr);

    // ---- phase 3: lap[c] = wu*up + wd*dn + wl*lf + wr*rt - wsum*center ----
    // (shifted values are 0 outside the image, but center is always subtracted)
    const float* up = u + pixoff;
    float*       op = out + pixoff;
    const bool hu = (i > 0), hd = (i < Hn - 1), hl = (j > 0), hr = (j < Wn - 1);

    #pragma unroll 2
    for (int c = 0; c < Cn; ++c) {
        const float* uc = up + (size_t)c * HWn;
        float uctr = uc[0];
        float uuu = hu ? uc[-Wn] : 0.0f;
        float uud = hd ? uc[ Wn] : 0.0f;
        float uul = hl ? uc[-1]  : 0.0f;
        float uur = hr ? uc[ 1]  : 0.0f;
        float lap = fmaf(wu, uuu,
                    fmaf(wd, uud,
                    fmaf(wl, uul,
                    fmaf(wr, uur, -wsum * uctr))));
        op[(size_t)c * HWn] = lap;
    }
}

extern "C" void kernel_launch(void* const* d_in, const int* in_sizes, int n_in,
                              void* d_out, int out_size, void* d_ws, size_t ws_size,
                              hipStream_t stream) {
    const float* u  = (const float*)d_in[0];
    const float* wi = (const float*)d_in[1];
    const float* w1 = (const float*)d_in[2];
    const float* b1 = (const float*)d_in[3];
    const float* w2 = (const float*)d_in[4];
    const float* b2 = (const float*)d_in[5];
    float* out = (float*)d_out;
    float* w1t = (float*)d_ws;   // 8192 floats = 32 KB

    prep_w1t<<<(ChN * Cn + 255) / 256, 256, 0, stream>>>(w1, w1t);

    int npix = Bn * Hn * Wn;     // 524288
    fused_lap<<<npix / 256, 256, 0, stream>>>(u, wi, w1t, b1, w2, b2, out);
}